// Round 15
// baseline (887.781 us; speedup 1.0000x reference)
//
#include <hip/hip_runtime.h>

// Problem: BiLSTM-CRF tagger NLL (forward only).
// B=64, L=128, E=300, H=256 (per dir), 4H=1024, T=64, V=50000.
//
// ws layout (float units):
//   XP_OFF   = 0           : xp[2][8192][1024] f32
//   LSTM_OFF = 16777216    : lstm_out[8192][512]
//   EM_OFF   = 20971520    : emissions[8192][64] (B-frag image + bias2 during
//                            xp_gemm — dead until emis_gemm)
//   WBF_OFF  = 21495808    : w_hh fp8 MFMA fragment image (512 KB)
//   NLL_OFF  = 21757952    : per-batch nll [64]
//
// R15: recurrence moved to fp8 MFMA. 8 blocks (dir x 4 groups of 16 batches),
// 512 thr. Wave w owns unit-groups {2w,2w+1} (= units 32w..32w+31), all 4
// gates, full K=256 -> 64 mfma_f32_16x16x32_fp8_fp8 per step, acc in-register
// (no partial exchange, ONE barrier/step). i,f frags LDS-cached (128KB);
// g,o streamed from L2 under exact counted vmcnt; h fp8(x4) in LDS,
// XOR-swizzled (unit ^ ((batch&3)<<3)) + double-buffered.
// Fragment mappings identical in index structure to the bf16 MFMA validated
// in xp_gemm (A: m=l&15,k=(l>>4)*8+j; B: n=l&15,k=(l>>4)*8+j; C: col=l&15,
// row=(l>>4)*4+reg). Scales: w x64, h x4 -> acc * 1/256.

#define XP_OFF   0
#define LSTM_OFF 16777216
#define EM_OFF   20971520
#define WBF_OFF  21495808
#define NLL_OFF  21757952
#define BIMG_OFF EM_OFF
#define BIAS_OFF (EM_OFF + 500000)

typedef unsigned v2u __attribute__((ext_vector_type(2)));
typedef unsigned v4u __attribute__((ext_vector_type(4)));
typedef short bf16x8 __attribute__((ext_vector_type(8)));
typedef float f32x4 __attribute__((ext_vector_type(4)));

__device__ __forceinline__ float sigmf(float x) { return 1.f / (1.f + __expf(-x)); }
__device__ __forceinline__ float tanhfast(float x) {
    float t = __expf(2.f * x);
    return 1.f - 2.f / (t + 1.f);
}
__device__ __forceinline__ unsigned short f2bf(float f) {
    unsigned u = __float_as_uint(f);
    return (unsigned short)((u + 0x7fffu + ((u >> 16) & 1u)) >> 16);
}
__device__ __forceinline__ unsigned packbf(float a, float b) {
    return (unsigned)f2bf(a) | ((unsigned)f2bf(b) << 16);
}
__device__ __forceinline__ long bc2(unsigned lo, unsigned hi) {
    v2u t; t.x = lo; t.y = hi;
    return __builtin_bit_cast(long, t);
}

// ---- fp8 e4m3fn encode (RNE), |x| <= 4.0 (validated path, used by cvt) ----
__device__ __forceinline__ unsigned enc8(float x) {
    unsigned s = (__float_as_uint(x) >> 31) << 7;
    float a = fabsf(x);
    if (a >= 0.015625f) {
        int e; float m = frexpf(a, &e);
        float q = rintf(m * 16.f);
        if (q >= 16.f) { q = 8.f; e += 1; }
        int E = e - 1 + 7;
        return s | (unsigned)(E << 3) | (unsigned)((int)q - 8);
    } else {
        float q = rintf(a * 512.f);
        if (q >= 8.f) return s | (1u << 3);
        return s | (unsigned)(int)q;
    }
}
// ---- fast e4m3fn encode for h (|x| <= 4, bit-twiddled RNE) ----
__device__ __forceinline__ unsigned char enc8fast(float x) {
    unsigned u = __float_as_uint(x);
    unsigned s = (u >> 24) & 0x80u;
    float a = fabsf(x);
    if (a >= 0.015625f) {
        unsigned ur = (u & 0x7FFFFFFFu) + 0x7FFFFu + ((u >> 20) & 1u);
        return (unsigned char)(s | (((ur >> 20) - 960u) & 0x7Fu));
    }
    return (unsigned char)(s | (unsigned)(int)rintf(a * 512.f));
}

// ---------------- K0: w_hh -> fp8 MFMA fragment image ----------------
// Cached region [0,256KB): byte c: dir=c>>17; r=c&0x1FFFF =
//   ((ug*8+kt)*64+lane)*16 + gate*8 + j   (gate 0=i,1=f)
// Streamed region [256KB,512KB): r = ((((w*2+gp)*2+ug1)*8+kt)*64+lane)*8 + j
//   (gate = 2+gp (g,o); ug = 2w+ug1)
// value = enc8( w_hh[gate*256 + ug*16 + (lane&15)][kt*32 + (lane>>4)*8 + j] *64 )
__global__ __launch_bounds__(256) void cvt_whh_frag(
    const float* __restrict__ wf, const float* __restrict__ wb,
    unsigned int* __restrict__ out)
{
    int tid8 = blockIdx.x * 256 + threadIdx.x;    // 0..65535, 8 bytes each
    unsigned byte0 = (unsigned)tid8 * 8u;
    int half = byte0 >> 18;
    int c = byte0 & 0x3FFFF;
    int dir = c >> 17;
    int r = c & 0x1FFFF;
    int gate, ug, lane, kt;
    if (half == 0) {
        gate = (r >> 3) & 1;
        lane = (r >> 4) & 63;
        kt   = (r >> 10) & 7;
        ug   = r >> 13;
    } else {
        lane = (r >> 3) & 63;
        kt   = (r >> 9) & 7;
        int ug1 = (r >> 12) & 1;
        int gp  = (r >> 13) & 1;
        int w   = r >> 14;
        gate = 2 + gp; ug = 2 * w + ug1;
    }
    const float* wsrc = dir ? wb : wf;
    int row = gate * 256 + ug * 16 + (lane & 15);
    int k0  = kt * 32 + (lane >> 4) * 8;
    const float* src = wsrc + (size_t)row * 256 + k0;
    unsigned lo = 0, hi = 0;
    #pragma unroll
    for (int j = 0; j < 4; ++j) {
        lo |= enc8(src[j] * 64.f) << (8 * j);
        hi |= enc8(src[4 + j] * 64.f) << (8 * j);
    }
    out[tid8 * 2]     = lo;
    out[tid8 * 2 + 1] = hi;
}

// ---------------- K0b: prep B fragment image + bias2 (unchanged) ------------
__global__ __launch_bounds__(64) void prep_b(
    const float* __restrict__ wf, const float* __restrict__ wb,
    const float* __restrict__ bif, const float* __restrict__ bhf,
    const float* __restrict__ bib, const float* __restrict__ bhb,
    unsigned* __restrict__ bimg, float* __restrict__ bias2)
{
    int n = blockIdx.x;
    int dir = n >> 10, nr = n & 1023;
    int k8 = threadIdx.x;
    if (k8 < 40) {
        const float* wsrc = dir ? wb : wf;
        float v[8];
        #pragma unroll
        for (int j = 0; j < 8; ++j) {
            int k = k8 * 8 + j;
            v[j] = (k < 300) ? wsrc[(size_t)nr * 300 + k] : 0.f;
        }
        int ntg = n >> 4, kt = k8 >> 2;
        int lane = ((k8 & 3) << 4) | (n & 15);
        unsigned* dst = bimg + (((size_t)(ntg * 10 + kt)) * 64 + lane) * 4;
        dst[0] = packbf(v[0], v[1]); dst[1] = packbf(v[2], v[3]);
        dst[2] = packbf(v[4], v[5]); dst[3] = packbf(v[6], v[7]);
    } else if (k8 == 40) {
        bias2[n] = (dir ? bib : bif)[nr] + (dir ? bhb : bhf)[nr];
    }
}

// ---------------- K1: xp GEMM via bf16 MFMA (unchanged, validated) ----------
__global__ __launch_bounds__(256) void xp_gemm(
    const int* __restrict__ sent, const float* __restrict__ emb,
    const unsigned* __restrict__ bimg, const float* __restrict__ bias2,
    float* __restrict__ xp)
{
    __shared__ __align__(16) unsigned short Alds[128 * 328];
    __shared__ int sidx[128];
    const int tid = threadIdx.x;
    const int m0 = blockIdx.x * 128;
    const int by = blockIdx.y;
    if (tid < 128) sidx[tid] = sent[m0 + tid];
    __syncthreads();
    #pragma unroll
    for (int i2 = 0; i2 < 5; ++i2) {
        int f2 = i2 * 256 + tid;
        int row = (f2 * 6554) >> 16;
        int d = f2 - row * 10;
        *(unsigned*)((char*)Alds + row * 656 + 600 + d * 4) = 0;
    }
    for (int it = 0; it < 38; ++it) {
        int f = it * 256 + tid;
        if (f < 9600) {
            int row = (int)(((unsigned)f * 55925u) >> 22);
            int c4 = f - row * 75;
            float4 v = *(const float4*)&emb[(size_t)sidx[row] * 300 + c4 * 4];
            uint2 p; p.x = packbf(v.x, v.y); p.y = packbf(v.z, v.w);
            *(uint2*)((char*)Alds + row * 656 + c4 * 8) = p;
        }
    }
    __syncthreads();
    const int l = tid & 63, wid = tid >> 6;
    const int wy = wid >> 1, wx = wid & 1;
    const int lhi = l >> 4, llo = l & 15;
    f32x4 acc[4][4];
    #pragma unroll
    for (int nt = 0; nt < 4; ++nt) {
        float bv = bias2[by * 128 + wx * 64 + nt * 16 + llo];
        #pragma unroll
        for (int mt = 0; mt < 4; ++mt) acc[mt][nt] = (f32x4){bv, bv, bv, bv};
    }
    const char* abase = (const char*)Alds + (size_t)(wy * 64 + llo) * 656 + lhi * 16;
    const unsigned* bb = bimg + (((size_t)((by * 8 + wx * 4) * 10)) * 64 + l) * 4;
    for (int kt = 0; kt < 10; ++kt) {
        bf16x8 a[4], b[4];
        #pragma unroll
        for (int mt = 0; mt < 4; ++mt)
            a[mt] = *(const bf16x8*)(abase + mt * 16 * 656 + kt * 64);
        #pragma unroll
        for (int nt = 0; nt < 4; ++nt)
            b[nt] = *(const bf16x8*)(bb + (nt * 10 + kt) * 256);
        #pragma unroll
        for (int mt = 0; mt < 4; ++mt)
            #pragma unroll
            for (int nt = 0; nt < 4; ++nt)
                acc[mt][nt] = __builtin_amdgcn_mfma_f32_16x16x32_bf16(
                    a[mt], b[nt], acc[mt][nt], 0, 0, 0);
    }
    const int dir = by >> 3;
    const int n0 = (by & 7) * 128 + wx * 64;
    float* outp = xp + (size_t)dir * 8388608;
    #pragma unroll
    for (int mt = 0; mt < 4; ++mt) {
        int row = m0 + wy * 64 + mt * 16 + lhi * 4;
        #pragma unroll
        for (int nt = 0; nt < 4; ++nt) {
            int col = n0 + nt * 16 + llo;
            #pragma unroll
            for (int j = 0; j < 4; ++j)
                outp[(size_t)(row + j) * 1024 + col] = acc[mt][nt][j];
        }
    }
}

// ---------------- K2: LSTM recurrence via fp8 MFMA ----------------
__global__ __launch_bounds__(512) void lstm_rec(
    const float* __restrict__ xp, const unsigned char* __restrict__ w8,
    float* __restrict__ lstm_out)
{
    const int bid = blockIdx.x;        // 0..7
    const int dir = bid >> 2;
    const int bg  = bid & 3;
    const int t = threadIdx.x;
    const int w = t >> 6;              // wave 0..7
    const int l = t & 63;
    const int b_ = l & 15;
    const int hi = l >> 4;             // 0..3
    __shared__ __align__(16) unsigned char hsb[8192];   // h fp8, 2 bufs x 16 x 256
    __shared__ __align__(16) unsigned char wl[131072];  // cached i,f frags

    // fill cached i,f frag image (dir's 128 KB), linear copy
    {
        const uint4* csrc = (const uint4*)(w8 + (size_t)dir * 131072);
        uint4* wld = (uint4*)wl;
        #pragma unroll
        for (int i = 0; i < 16; ++i) wld[t + i * 512] = csrc[t + i * 512];
    }
    // zero h buf0
    ((unsigned*)hsb)[t] = 0;
    ((unsigned*)hsb)[t + 512] = 0;

    // streamed g,o bases (13-bit signed offsets)
    const unsigned char* sreg = w8 + 262144 + (size_t)dir * 131072 + (size_t)w * 16384;
    const unsigned char* sbG = sreg + 4096 + l * 8;
    const unsigned char* sbO = sreg + 12288 + l * 8;
    // LDS bases
    const unsigned wbase = (unsigned)(size_t)&wl[0] + (unsigned)(w * 16384 + l * 16);
    unsigned habase = (unsigned)(size_t)&hsb[0]
                    + (unsigned)(b_ * 256 + ((hi ^ (l & 3)) << 3));
    unsigned char* hflat = hsb;
    unsigned pw4096 = 4096;            // write buffer byte offset (buf1 first)
    const int mb0 = 4 * hi;
    const unsigned u0 = 32 * w + b_;

    const int dl = dir ? -1 : 1;
    const int l0 = dir ? 127 : 0;
    const float* xr0 = xp + (size_t)dir * 8388608
                     + ((size_t)((16 * bg + mb0 + 0) * 128 + l0)) * 1024 + u0;
    const float* xr1 = xr0 + 131072;
    const float* xr2 = xr0 + 262144;
    const float* xr3 = xr0 + 393216;
    float* lo0 = lstm_out + ((size_t)((16 * bg + mb0 + 0) * 128 + l0)) * 512
               + dir * 256 + u0;
    float* lo1 = lo0 + 65536;
    float* lo2 = lo0 + 131072;
    float* lo3 = lo0 + 196608;

    float cA0 = 0.f, cA1 = 0.f, cA2 = 0.f, cA3 = 0.f;
    float cB0 = 0.f, cB1 = 0.f, cB2 = 0.f, cB3 = 0.f;
    __syncthreads();

#define WAITL(N) { asm volatile("s_waitcnt lgkmcnt(" #N ")" ::: "memory"); \
                   __builtin_amdgcn_sched_barrier(0); }
#define WAITV(N) { asm volatile("s_waitcnt vmcnt(" #N ")" ::: "memory"); \
                   __builtin_amdgcn_sched_barrier(0); }
#define ISSUE(AV, FA, FB, GA, OA, GB, OB, AOFF, WOFF, W2OFF, GAOFF, GBOFF) \
  asm volatile("ds_read_b64 %0, %1 offset:" AOFF : "=&v"(AV) : "v"(habase)); \
  asm volatile("ds_read_b128 %0, %1 offset:" WOFF : "=&v"(FA) : "v"(wbase)); \
  asm volatile("ds_read_b128 %0, %1 offset:" W2OFF : "=&v"(FB) : "v"(wbase)); \
  asm volatile("global_load_dwordx2 %0, %1, off offset:" GAOFF : "=&v"(GA) : "v"(sbG)); \
  asm volatile("global_load_dwordx2 %0, %1, off offset:" GBOFF : "=&v"(GB) : "v"(sbG)); \
  asm volatile("global_load_dwordx2 %0, %1, off offset:" GAOFF : "=&v"(OA) : "v"(sbO)); \
  asm volatile("global_load_dwordx2 %0, %1, off offset:" GBOFF : "=&v"(OB) : "v"(sbO));
#define MFMA8(AV, FA, FB, GA, OA, GB, OB) { \
  long a_ = __builtin_bit_cast(long, AV); \
  accAi = __builtin_amdgcn_mfma_f32_16x16x32_fp8_fp8(a_, bc2(FA.x, FA.y), accAi, 0, 0, 0); \
  accAf = __builtin_amdgcn_mfma_f32_16x16x32_fp8_fp8(a_, bc2(FA.z, FA.w), accAf, 0, 0, 0); \
  accAg = __builtin_amdgcn_mfma_f32_16x16x32_fp8_fp8(a_, __builtin_bit_cast(long, GA), accAg, 0, 0, 0); \
  accAo = __builtin_amdgcn_mfma_f32_16x16x32_fp8_fp8(a_, __builtin_bit_cast(long, OA), accAo, 0, 0, 0); \
  accBi = __builtin_amdgcn_mfma_f32_16x16x32_fp8_fp8(a_, bc2(FB.x, FB.y), accBi, 0, 0, 0); \
  accBf = __builtin_amdgcn_mfma_f32_16x16x32_fp8_fp8(a_, bc2(FB.z, FB.w), accBf, 0, 0, 0); \
  accBg = __builtin_amdgcn_mfma_f32_16x16x32_fp8_fp8(a_, __builtin_bit_cast(long, GB), accBg, 0, 0, 0); \
  accBo = __builtin_amdgcn_mfma_f32_16x16x32_fp8_fp8(a_, __builtin_bit_cast(long, OB), accBo, 0, 0, 0); }
#define XPL(PTR, A, B, C, D, E, F, G, H) \
  asm volatile("global_load_dword %0, %8, off\n\t" \
               "global_load_dword %1, %8, off offset:64\n\t" \
               "global_load_dword %2, %8, off offset:1024\n\t" \
               "global_load_dword %3, %8, off offset:1088\n\t" \
               "global_load_dword %4, %8, off offset:2048\n\t" \
               "global_load_dword %5, %8, off offset:2112\n\t" \
               "global_load_dword %6, %8, off offset:3072\n\t" \
               "global_load_dword %7, %8, off offset:3136" \
               : "=&v"(A), "=&v"(B), "=&v"(C), "=&v"(D), \
                 "=&v"(E), "=&v"(F), "=&v"(G), "=&v"(H) : "v"(PTR));
#define ACT(REG, UGI, CV, XI, XF, XG, XO, ACCI, ACCF, ACCG, ACCO, LOP) { \
  float gi = fmaf(ACCI[REG], 0.00390625f, XI); \
  float gf = fmaf(ACCF[REG], 0.00390625f, XF); \
  float gg = fmaf(ACCG[REG], 0.00390625f, XG); \
  float go = fmaf(ACCO[REG], 0.00390625f, XO); \
  CV = sigmf(gf) * CV + sigmf(gi) * tanhfast(gg); \
  float h_ = sigmf(go) * tanhfast(CV); \
  LOP[(UGI) * 16] = h_; \
  unsigned u_ = u0 + (UGI) * 16; \
  hflat[pw4096 + (mb0 + (REG)) * 256 + (u_ ^ ((REG) << 3))] = enc8fast(h_ * 4.f); }

    for (int s = 0; s < 128; ++s) {
        f32x4 accAi = {0,0,0,0}, accAf = {0,0,0,0}, accAg = {0,0,0,0}, accAo = {0,0,0,0};
        f32x4 accBi = {0,0,0,0}, accBf = {0,0,0,0}, accBg = {0,0,0,0}, accBo = {0,0,0,0};
        v2u A0, A1, G0a, G0b, O0a, O0b, G1a, G1b, O1a, O1b;
        v4u F0a, F0b, F1a, F1b;
        ISSUE(A0, F0a, F0b, G0a, O0a, G0b, O0b, "0",   "0",    "8192",  "-4096", "0")
        ISSUE(A1, F1a, F1b, G1a, O1a, G1b, O1b, "32",  "1024", "9216",  "-3584", "512")
        WAITL(3); WAITV(4);
        MFMA8(A0, F0a, F0b, G0a, O0a, G0b, O0b)
        ISSUE(A0, F0a, F0b, G0a, O0a, G0b, O0b, "64",  "2048", "10240", "-3072", "1024")
        WAITL(3); WAITV(4);
        MFMA8(A1, F1a, F1b, G1a, O1a, G1b, O1b)
        ISSUE(A1, F1a, F1b, G1a, O1a, G1b, O1b, "96",  "3072", "11264", "-2560", "1536")
        WAITL(3); WAITV(4);
        MFMA8(A0, F0a, F0b, G0a, O0a, G0b, O0b)
        ISSUE(A0, F0a, F0b, G0a, O0a, G0b, O0b, "128", "4096", "12288", "-2048", "2048")
        WAITL(3); WAITV(4);
        MFMA8(A1, F1a, F1b, G1a, O1a, G1b, O1b)
        ISSUE(A1, F1a, F1b, G1a, O1a, G1b, O1b, "160", "5120", "13312", "-1536", "2560")
        WAITL(3); WAITV(4);
        MFMA8(A0, F0a, F0b, G0a, O0a, G0b, O0b)
        ISSUE(A0, F0a, F0b, G0a, O0a, G0b, O0b, "192", "6144", "14336", "-1024", "3072")
        WAITL(3); WAITV(4);
        MFMA8(A1, F1a, F1b, G1a, O1a, G1b, O1b)
        ISSUE(A1, F1a, F1b, G1a, O1a, G1b, O1b, "224", "7168", "15360", "-512",  "3584")
        WAITL(3); WAITV(4);
        MFMA8(A0, F0a, F0b, G0a, O0a, G0b, O0b)
        WAITL(0); WAITV(0);
        MFMA8(A1, F1a, F1b, G1a, O1a, G1b, O1b)

        // xp loads (queue now empty -> WAITV(0) below waits exactly these)
        float x0ia, x0ib, x0fa, x0fb, x0ga, x0gb, x0oa, x0ob;
        float x1ia, x1ib, x1fa, x1fb, x1ga, x1gb, x1oa, x1ob;
        float x2ia, x2ib, x2fa, x2fb, x2ga, x2gb, x2oa, x2ob;
        float x3ia, x3ib, x3fa, x3fb, x3ga, x3gb, x3oa, x3ob;
        XPL(xr0, x0ia, x0ib, x0fa, x0fb, x0ga, x0gb, x0oa, x0ob)
        XPL(xr1, x1ia, x1ib, x1fa, x1fb, x1ga, x1gb, x1oa, x1ob)
        XPL(xr2, x2ia, x2ib, x2fa, x2fb, x2ga, x2gb, x2oa, x2ob)
        XPL(xr3, x3ia, x3ib, x3fa, x3fb, x3ga, x3gb, x3oa, x3ob)
        WAITV(0);
        ACT(0, 0, cA0, x0ia, x0fa, x0ga, x0oa, accAi, accAf, accAg, accAo, lo0)
        ACT(0, 1, cB0, x0ib, x0fb, x0gb, x0ob, accBi, accBf, accBg, accBo, lo0)
        ACT(1, 0, cA1, x1ia, x1fa, x1ga, x1oa, accAi, accAf, accAg, accAo, lo1)
        ACT(1, 1, cB1, x1ib, x1fb, x1gb, x1ob, accBi, accBf, accBg, accBo, lo1)
        ACT(2, 0, cA2, x2ia, x2fa, x2ga, x2oa, accAi, accAf, accAg, accAo, lo2)
        ACT(2, 1, cB2, x2ib, x2fb, x2gb, x2ob, accBi, accBf, accBg, accBo, lo2)
        ACT(3, 0, cA3, x3ia, x3fa, x3ga, x3oa, accAi, accAf, accAg, accAo, lo3)
        ACT(3, 1, cB3, x3ib, x3fb, x3gb, x3ob, accBi, accBf, accBg, accBo, lo3)
        __builtin_amdgcn_sched_barrier(0);
        __syncthreads();
        __builtin_amdgcn_sched_barrier(0);
        habase ^= 4096u; pw4096 ^= 4096u;
        xr0 += (ptrdiff_t)dl * 1024; xr1 += (ptrdiff_t)dl * 1024;
        xr2 += (ptrdiff_t)dl * 1024; xr3 += (ptrdiff_t)dl * 1024;
        lo0 += (ptrdiff_t)dl * 512;  lo1 += (ptrdiff_t)dl * 512;
        lo2 += (ptrdiff_t)dl * 512;  lo3 += (ptrdiff_t)dl * 512;
    }
#undef WAITL
#undef WAITV
#undef ISSUE
#undef MFMA8
#undef XPL
#undef ACT
}

// ---------------- K3: emissions GEMM (unchanged) ----------------
__global__ __launch_bounds__(256) void emis_gemm(
    const float* __restrict__ lo, const float* __restrict__ w_out,
    const float* __restrict__ b_out, float* __restrict__ em)
{
    __shared__ float as[64][64];
    __shared__ float bs[64][64];
    const int tid = threadIdx.x;
    const int m0 = blockIdx.x * 64;
    const int mr = tid & 63;
    const int kq = tid >> 6;
    const int rb = (tid & 15) * 4;
    const int cb = (tid >> 4) * 4;
    float acc[4][4] = {};
    for (int kc = 0; kc < 8; ++kc) {
        const int k0 = kc * 64;
        #pragma unroll
        for (int i = 0; i < 4; ++i) {
            const int k = kq * 16 + 4 * i;
            float4 va = *(const float4*)&lo[(size_t)(m0 + mr) * 512 + k0 + k];
            as[k][mr] = va.x; as[k + 1][mr] = va.y; as[k + 2][mr] = va.z; as[k + 3][mr] = va.w;
            float4 vb = *(const float4*)&w_out[(size_t)mr * 512 + k0 + k];
            bs[k][mr] = vb.x; bs[k + 1][mr] = vb.y; bs[k + 2][mr] = vb.z; bs[k + 3][mr] = vb.w;
        }
        __syncthreads();
        #pragma unroll 8
        for (int kk = 0; kk < 64; ++kk) {
            float a[4], bb[4];
            *(float4*)a  = *(const float4*)&as[kk][rb];
            *(float4*)bb = *(const float4*)&bs[kk][cb];
            #pragma unroll
            for (int i = 0; i < 4; ++i)
                #pragma unroll
                for (int jj = 0; jj < 4; ++jj)
                    acc[i][jj] += a[i] * bb[jj];
        }
        __syncthreads();
    }
    float4 bo = *(const float4*)&b_out[cb];
    #pragma unroll
    for (int i = 0; i < 4; ++i) {
        float4 o = make_float4(acc[i][0] + bo.x, acc[i][1] + bo.y,
                               acc[i][2] + bo.z, acc[i][3] + bo.w);
        *(float4*)&em[(size_t)(m0 + rb + i) * 64 + cb] = o;
    }
}

// ---------------- K4: CRF numerator + forward algorithm (unchanged) ---------
__global__ __launch_bounds__(256) void crf_kernel(
    const float* __restrict__ em, const int* __restrict__ tags,
    const float* __restrict__ start_t, const float* __restrict__ end_t,
    const float* __restrict__ trans, float* __restrict__ nll)
{
    const int b = blockIdx.x;
    const int tid = threadIdx.x;
    const int j = tid & 63;
    const int q = tid >> 6;
    __shared__ float s_lds[64];
    __shared__ float part[4][64];
    __shared__ float m_sh, num_sh;
    float tr[16];
    #pragma unroll
    for (int ii = 0; ii < 16; ++ii) tr[ii] = trans[(q * 16 + ii) * 64 + j];
    const float* emb_b = em + (size_t)b * 8192;
    const int* tg_b = tags + b * 128;
    float numpart = 0.f;
    if (tid < 128) {
        int l = tid;
        int tg = tg_b[l];
        numpart = emb_b[l * 64 + tg];
        if (l < 127) numpart += trans[tg * 64 + tg_b[l + 1]];
        if (l == 0)  numpart += start_t[tg];
        if (l == 127) numpart += end_t[tg];
    }
    float red = numpart;
    #pragma unroll
    for (int off = 32; off >= 1; off >>= 1) red += __shfl_xor(red, off);
    if (j == 0) part[q][0] = red;
    if (q == 0) s_lds[j] = start_t[j] + emb_b[j];
    __syncthreads();
    if (tid == 0) num_sh = part[0][0] + part[1][0] + part[2][0] + part[3][0];
    __syncthreads();
    for (int l = 1; l < 128; ++l) {
        if (q == 0) {
            float v = s_lds[j];
            #pragma unroll
            for (int off = 32; off >= 1; off >>= 1) v = fmaxf(v, __shfl_xor(v, off));
            if (j == 0) m_sh = v;
        }
        __syncthreads();
        const float m = m_sh;
        float sv[16];
        #pragma unroll
        for (int t4 = 0; t4 < 4; ++t4) {
            float4 v = *(const float4*)&s_lds[q * 16 + 4 * t4];
            sv[4 * t4] = v.x; sv[4 * t4 + 1] = v.y; sv[4 * t4 + 2] = v.z; sv[4 * t4 + 3] = v.w;
        }
        float acc = 0.f;
        #pragma unroll
        for (int ii = 0; ii < 16; ++ii) acc += __expf(sv[ii] + tr[ii] - m);
        part[q][j] = acc;
        __syncthreads();
        if (q == 0) {
            float t = part[0][j] + part[1][j] + part[2][j] + part[3][j];
            s_lds[j] = m + __logf(t) + emb_b[l * 64 + j];
        }
    }
    if (q == 0) {
        float v = s_lds[j] + end_t[j];
        float mm = v;
        #pragma unroll
        for (int off = 32; off >= 1; off >>= 1) mm = fmaxf(mm, __shfl_xor(mm, off));
        float e = __expf(v - mm);
        #pragma unroll
        for (int off = 32; off >= 1; off >>= 1) e += __shfl_xor(e, off);
        if (j == 0) nll[b] = (mm + __logf(e)) - num_sh;
    }
}

// ---------------- K5: final mean ----------------
__global__ void finalize(const float* __restrict__ nll, float* __restrict__ out)
{
    int j = threadIdx.x;
    float v = nll[j];
    #pragma unroll
    for (int off = 32; off >= 1; off >>= 1) v += __shfl_xor(v, off);
    if (j == 0) out[0] = v * (1.f / 64.f);
}

extern "C" void kernel_launch(void* const* d_in, const int* in_sizes, int n_in,
                              void* d_out, int out_size, void* d_ws, size_t ws_size,
                              hipStream_t stream) {
    const int* sent      = (const int*)d_in[0];
    const int* tags      = (const int*)d_in[1];
    const float* emb     = (const float*)d_in[2];
    const float* w_ih_f  = (const float*)d_in[3];
    const float* w_hh_f  = (const float*)d_in[4];
    const float* b_ih_f  = (const float*)d_in[5];
    const float* b_hh_f  = (const float*)d_in[6];
    const float* w_ih_b  = (const float*)d_in[7];
    const float* w_hh_b  = (const float*)d_in[8];
    const float* b_ih_b  = (const float*)d_in[9];
    const float* b_hh_b  = (const float*)d_in[10];
    const float* w_out   = (const float*)d_in[11];
    const float* b_out   = (const float*)d_in[12];
    const float* start_t = (const float*)d_in[13];
    const float* end_t   = (const float*)d_in[14];
    const float* trans   = (const float*)d_in[15];

    float* ws = (float*)d_ws;
    float* xp        = ws + XP_OFF;
    float* lstm_out  = ws + LSTM_OFF;
    float* em        = ws + EM_OFF;
    unsigned int* w8 = (unsigned int*)(ws + WBF_OFF);
    float* nll       = ws + NLL_OFF;
    unsigned* bimg   = (unsigned*)(ws + BIMG_OFF);
    float* bias2     = ws + BIAS_OFF;

    cvt_whh_frag<<<dim3(256), dim3(256), 0, stream>>>(w_hh_f, w_hh_b, w8);
    prep_b<<<dim3(2048), dim3(64), 0, stream>>>(w_ih_f, w_ih_b,
        b_ih_f, b_hh_f, b_ih_b, b_hh_b, bimg, bias2);
    xp_gemm<<<dim3(64, 16), dim3(256), 0, stream>>>(sent, emb, bimg, bias2, xp);
    lstm_rec<<<dim3(8), dim3(512), 0, stream>>>(xp, (const unsigned char*)w8, lstm_out);
    emis_gemm<<<dim3(128), dim3(256), 0, stream>>>(lstm_out, w_out, b_out, em);
    crf_kernel<<<dim3(64), dim3(256), 0, stream>>>(em, tags, start_t, end_t, trans, nll);
    finalize<<<dim3(1), dim3(64), 0, stream>>>(nll, (float*)d_out);
}

// Round 16
// 428.730 us; speedup vs baseline: 2.0707x; 2.0707x over previous
//
#include <hip/hip_runtime.h>

// Problem: BiLSTM-CRF tagger NLL (forward only).
// B=64, L=128, E=300, H=256 (per dir), 4H=1024, T=64, V=50000.
//
// ws layout (float units):
//   XP_OFF   = 0           : xp[2][8192][1024] f32
//   LSTM_OFF = 16777216    : lstm_out[8192][512]
//   EM_OFF   = 20971520    : emissions[8192][64] (B-frag image + bias2 during
//                            xp_gemm — dead until emis_gemm)
//   WBF_OFF  = 21495808    : w_hh int8, wave-coalesced uint4 layout (512 KB)
//   NLL_OFF  = 21757952    : per-batch nll [64]
//
// R15 lesson: MFMA M=16 forces 16 chains/block -> 8 blocks = 8 CUs (0.76%
// occupancy), latency-serialized. Recurrence stays on 128 blocks (1 chain
// each). R16: R14's proven skeleton (512 thr, VGPR 88, counted vmcnt) with
// int8 arithmetic: w x2016, h x127, v_dot4_i32_i8 (4 MACs/inst). VALU/step
// 544 -> ~190 inst; h bf16->i8 halves h DS reads. Accuracy better than fp8.

#define XP_OFF   0
#define LSTM_OFF 16777216
#define EM_OFF   20971520
#define WBF_OFF  21495808
#define NLL_OFF  21757952
#define BIMG_OFF EM_OFF
#define BIAS_OFF (EM_OFF + 500000)

typedef unsigned v4u __attribute__((ext_vector_type(4)));
typedef short bf16x8 __attribute__((ext_vector_type(8)));
typedef float f32x4 __attribute__((ext_vector_type(4)));

__device__ __forceinline__ float sigmf(float x) { return 1.f / (1.f + __expf(-x)); }
__device__ __forceinline__ float tanhfast(float x) {
    float t = __expf(2.f * x);
    return 1.f - 2.f / (t + 1.f);
}
__device__ __forceinline__ unsigned short f2bf(float f) {
    unsigned u = __float_as_uint(f);
    return (unsigned short)((u + 0x7fffu + ((u >> 16) & 1u)) >> 16);
}
__device__ __forceinline__ unsigned packbf(float a, float b) {
    return (unsigned)f2bf(a) | ((unsigned)f2bf(b) << 16);
}
__device__ __forceinline__ int dot4(int a, int b, int c) {
#if __has_builtin(__builtin_amdgcn_sdot4)
    return __builtin_amdgcn_sdot4(a, b, c, false);
#else
    int r = c;
    #pragma unroll
    for (int i = 0; i < 4; ++i) {
        int ai = (a << (24 - 8 * i)) >> 24;
        int bi = (b << (24 - 8 * i)) >> 24;
        r += ai * bi;
    }
    return r;
#endif
}
// int8 encode for w_hh (|w| <= 1/16 -> |w*2016| <= 126)
__device__ __forceinline__ unsigned ei8(float x) {
    float v = fminf(fmaxf(x * 2016.f, -127.f), 127.f);
    return (unsigned)(unsigned char)(signed char)(int)rintf(v);
}

// ---------------- K0: repack w_hh (f32 -> int8, scaled x2016) ---------------
// Quad index = half*16384 + ((dir*8 + w)*16 + q)*64 + ln   (same layout as
// R14's fp8 image; only the byte encoding changed).
//   half0 (i,f; LDS-cached): gate = q>>3, sc = q&7
//   half1 (g,o; streamed)  : gate = 2+(q&1), sc = q>>1
//   dword i covers k = kh*128 + sc*16 + i*4 .. +3 of row gate*256+r,
//   thread t = w*64+ln: r = t&255, kh = t>>8.
__global__ __launch_bounds__(256) void cvt_whh_i8(
    const float* __restrict__ wf, const float* __restrict__ wb,
    unsigned int* __restrict__ out)
{
    int idx = blockIdx.x * 256 + threadIdx.x;   // dword 0..131071
    int i    = idx & 3;
    int ln   = (idx >> 2) & 63;
    int q    = (idx >> 8) & 15;
    int w    = (idx >> 12) & 7;
    int dir  = (idx >> 15) & 1;
    int half = (idx >> 16) & 1;
    const float* wsrc = dir ? wb : wf;
    int t = w * 64 + ln;
    int r = t & 255, kh = t >> 8;
    int g_, sc;
    if (half == 0) { g_ = q >> 3;       sc = q & 7;  }
    else           { g_ = 2 + (q & 1);  sc = q >> 1; }
    int row = g_ * 256 + r;
    int k0 = kh * 128 + sc * 16 + i * 4;
    const float* src = wsrc + (size_t)row * 256 + k0;
    unsigned o = 0;
    #pragma unroll
    for (int j = 0; j < 4; ++j) o |= ei8(src[j]) << (8 * j);
    out[idx] = o;
}

// ---------------- K0b: prep B fragment image + bias2 (unchanged) ------------
__global__ __launch_bounds__(64) void prep_b(
    const float* __restrict__ wf, const float* __restrict__ wb,
    const float* __restrict__ bif, const float* __restrict__ bhf,
    const float* __restrict__ bib, const float* __restrict__ bhb,
    unsigned* __restrict__ bimg, float* __restrict__ bias2)
{
    int n = blockIdx.x;
    int dir = n >> 10, nr = n & 1023;
    int k8 = threadIdx.x;
    if (k8 < 40) {
        const float* wsrc = dir ? wb : wf;
        float v[8];
        #pragma unroll
        for (int j = 0; j < 8; ++j) {
            int k = k8 * 8 + j;
            v[j] = (k < 300) ? wsrc[(size_t)nr * 300 + k] : 0.f;
        }
        int ntg = n >> 4, kt = k8 >> 2;
        int lane = ((k8 & 3) << 4) | (n & 15);
        unsigned* dst = bimg + (((size_t)(ntg * 10 + kt)) * 64 + lane) * 4;
        dst[0] = packbf(v[0], v[1]); dst[1] = packbf(v[2], v[3]);
        dst[2] = packbf(v[4], v[5]); dst[3] = packbf(v[6], v[7]);
    } else if (k8 == 40) {
        bias2[n] = (dir ? bib : bif)[nr] + (dir ? bhb : bhf)[nr];
    }
}

// ---------------- K1: xp GEMM via bf16 MFMA (unchanged, validated) ----------
__global__ __launch_bounds__(256) void xp_gemm(
    const int* __restrict__ sent, const float* __restrict__ emb,
    const unsigned* __restrict__ bimg, const float* __restrict__ bias2,
    float* __restrict__ xp)
{
    __shared__ __align__(16) unsigned short Alds[128 * 328];
    __shared__ int sidx[128];
    const int tid = threadIdx.x;
    const int m0 = blockIdx.x * 128;
    const int by = blockIdx.y;
    if (tid < 128) sidx[tid] = sent[m0 + tid];
    __syncthreads();
    #pragma unroll
    for (int i2 = 0; i2 < 5; ++i2) {
        int f2 = i2 * 256 + tid;
        int row = (f2 * 6554) >> 16;
        int d = f2 - row * 10;
        *(unsigned*)((char*)Alds + row * 656 + 600 + d * 4) = 0;
    }
    for (int it = 0; it < 38; ++it) {
        int f = it * 256 + tid;
        if (f < 9600) {
            int row = (int)(((unsigned)f * 55925u) >> 22);
            int c4 = f - row * 75;
            float4 v = *(const float4*)&emb[(size_t)sidx[row] * 300 + c4 * 4];
            uint2 p; p.x = packbf(v.x, v.y); p.y = packbf(v.z, v.w);
            *(uint2*)((char*)Alds + row * 656 + c4 * 8) = p;
        }
    }
    __syncthreads();
    const int l = tid & 63, wid = tid >> 6;
    const int wy = wid >> 1, wx = wid & 1;
    const int lhi = l >> 4, llo = l & 15;
    f32x4 acc[4][4];
    #pragma unroll
    for (int nt = 0; nt < 4; ++nt) {
        float bv = bias2[by * 128 + wx * 64 + nt * 16 + llo];
        #pragma unroll
        for (int mt = 0; mt < 4; ++mt) acc[mt][nt] = (f32x4){bv, bv, bv, bv};
    }
    const char* abase = (const char*)Alds + (size_t)(wy * 64 + llo) * 656 + lhi * 16;
    const unsigned* bb = bimg + (((size_t)((by * 8 + wx * 4) * 10)) * 64 + l) * 4;
    for (int kt = 0; kt < 10; ++kt) {
        bf16x8 a[4], b[4];
        #pragma unroll
        for (int mt = 0; mt < 4; ++mt)
            a[mt] = *(const bf16x8*)(abase + mt * 16 * 656 + kt * 64);
        #pragma unroll
        for (int nt = 0; nt < 4; ++nt)
            b[nt] = *(const bf16x8*)(bb + (nt * 10 + kt) * 256);
        #pragma unroll
        for (int mt = 0; mt < 4; ++mt)
            #pragma unroll
            for (int nt = 0; nt < 4; ++nt)
                acc[mt][nt] = __builtin_amdgcn_mfma_f32_16x16x32_bf16(
                    a[mt], b[nt], acc[mt][nt], 0, 0, 0);
    }
    const int dir = by >> 3;
    const int n0 = (by & 7) * 128 + wx * 64;
    float* outp = xp + (size_t)dir * 8388608;
    #pragma unroll
    for (int mt = 0; mt < 4; ++mt) {
        int row = m0 + wy * 64 + mt * 16 + lhi * 4;
        #pragma unroll
        for (int nt = 0; nt < 4; ++nt) {
            int col = n0 + nt * 16 + llo;
            #pragma unroll
            for (int j = 0; j < 4; ++j)
                outp[(size_t)(row + j) * 1024 + col] = acc[mt][nt][j];
        }
    }
}

// ---------------- K2: LSTM recurrence, int8 dot4 ----------------
// 128 blocks = (dir, batch), dir = (bid&7)>>2.  512 threads.
// Thread t: r = t&255 (unit), kh = t>>8. Owns all 4 gates of unit r over
// k in [kh*128, kh*128+128) = 8 subchunks of 16 k.
// i,f weights LDS-cached (128 KB); g,o streamed from L2 under exact counted
// vmcnt (R14's schedule); h int8 in LDS (1 uniform b128 per sc).
__global__ __launch_bounds__(512) void lstm_rec(
    const float* __restrict__ xp, const unsigned int* __restrict__ w8,
    float* __restrict__ lstm_out)
{
    const int bid = blockIdx.x;
    const int r8  = bid & 7;
    const int dir = r8 >> 2;
    const int b   = ((bid >> 3) << 2) | (r8 & 3);
    const int t  = threadIdx.x;
    const int w  = t >> 6;      // 0..7
    const int ln = t & 63;
    const int r  = t & 255;
    const int kh = t >> 8;      // 0..1, uniform per wave
    __shared__ __align__(16) unsigned char hs[256];    // h int8 (x127)
    __shared__ __align__(16) float part2[2][256][4];   // [kh][unit][gate]
    __shared__ v4u wl[8192];                           // 128 KB cached i,f

    const v4u* w4 = (const v4u*)w8;
    #pragma unroll
    for (int q = 0; q < 16; ++q)
        wl[(w * 16 + q) * 64 + ln] = w4[((size_t)(dir * 8 + w) * 16 + q) * 64 + ln];

    // streamed bases (13-bit signed offsets): A covers q0..7, B covers q8..15
    const v4u* sbA = w4 + 16384 + ((size_t)(dir * 8 + w) * 16 + 4)  * 64 + ln;
    const v4u* sbB = w4 + 16384 + ((size_t)(dir * 8 + w) * 16 + 12) * 64 + ln;
    const unsigned wofs = (unsigned)(size_t)&wl[0] + (unsigned)(w * 16384 + ln * 16);
    const unsigned hofs = (unsigned)(size_t)&hs[0] + (unsigned)(kh * 128);

    float c = 0.f;
    if (t < 64) ((unsigned*)hs)[t] = 0;
    const float* xpb = xp + (size_t)dir * 8388608 + (size_t)b * 131072;
    const int dl = dir ? -1 : 1;
    int l = dir ? 127 : 0;
    float* lob = lstm_out + (size_t)b * 65536 + dir * 256 + r;
    __syncthreads();

#define LDGA(reg, off) asm volatile("global_load_dwordx4 %0, %1, off offset:" off \
                                    : "=&v"(reg) : "v"(sbA))
#define LDGB(reg, off) asm volatile("global_load_dwordx4 %0, %1, off offset:" off \
                                    : "=&v"(reg) : "v"(sbB))
#define DSH(reg, off) asm volatile("ds_read_b128 %0, %1 offset:" off \
                                   : "=&v"(reg) : "v"(hofs))
#define DSW2(ri, rf, oi, of) asm volatile( \
    "ds_read_b128 %0, %2 offset:" oi "\n\t" \
    "ds_read_b128 %1, %2 offset:" of \
    : "=&v"(ri), "=&v"(rf) : "v"(wofs))
#define WAITL(N) { asm volatile("s_waitcnt lgkmcnt(" #N ")" ::: "memory"); \
                   __builtin_amdgcn_sched_barrier(0); }
#define WAITV(N) { asm volatile("s_waitcnt vmcnt(" #N ")" ::: "memory"); \
                   __builtin_amdgcn_sched_barrier(0); }
#define DOT16(H, WI, WF, G, O) { \
    ai = dot4((int)H[0], (int)WI[0], ai); af = dot4((int)H[0], (int)WF[0], af); \
    ag = dot4((int)H[0], (int)G[0], ag);  ao = dot4((int)H[0], (int)O[0], ao); \
    ai = dot4((int)H[1], (int)WI[1], ai); af = dot4((int)H[1], (int)WF[1], af); \
    ag = dot4((int)H[1], (int)G[1], ag);  ao = dot4((int)H[1], (int)O[1], ao); \
    ai = dot4((int)H[2], (int)WI[2], ai); af = dot4((int)H[2], (int)WF[2], af); \
    ag = dot4((int)H[2], (int)G[2], ag);  ao = dot4((int)H[2], (int)O[2], ao); \
    ai = dot4((int)H[3], (int)WI[3], ai); af = dot4((int)H[3], (int)WF[3], af); \
    ag = dot4((int)H[3], (int)G[3], ag);  ao = dot4((int)H[3], (int)O[3], ao); }

    for (int s = 0; s < 128; ++s) {
        // ---- issue 8 streamed g/o quads (sc0-3, vmcnt-oldest), then xp ----
        v4u g0, o0, g1, o1, g2, o2, g3, o3;
        LDGA(g0, "-4096"); LDGA(o0, "-3072"); LDGA(g1, "-2048"); LDGA(o1, "-1024");
        LDGA(g2, "0");     LDGA(o2, "1024");  LDGA(g3, "2048");  LDGA(o3, "3072");
        float x0, x1, x2, x3;                 // all threads (uniform vmcnt queue)
        {
            const float* xcur = xpb + (size_t)l * 1024 + r;
            asm volatile("global_load_dword %0, %4, off\n\t"
                         "global_load_dword %1, %4, off offset:1024\n\t"
                         "global_load_dword %2, %4, off offset:2048\n\t"
                         "global_load_dword %3, %4, off offset:3072"
                         : "=&v"(x0), "=&v"(x1), "=&v"(x2), "=&v"(x3) : "v"(xcur));
        }
        // VMEM queue: g0,o0,g1,o1,g2,o2,g3,o3,x0..x3, then 8 in-loop LDGB
        int ai = 0, af = 0, ag = 0, ao = 0;
        v4u hA, hB, wiA, wfA, wiB, wfB;
        DSH(hA, "0");  DSW2(wiA, wfA, "0", "8192");
        DSH(hB, "16"); DSW2(wiB, wfB, "1024", "9216");
        // sc0
        WAITL(3); WAITV(10);
        DOT16(hA, wiA, wfA, g0, o0)
        LDGB(g0, "-4096"); LDGB(o0, "-3072");      // sc4
        DSH(hA, "32"); DSW2(wiA, wfA, "2048", "10240");
        // sc1
        WAITL(3); WAITV(10);
        DOT16(hB, wiB, wfB, g1, o1)
        LDGB(g1, "-2048"); LDGB(o1, "-1024");      // sc5
        DSH(hB, "48"); DSW2(wiB, wfB, "3072", "11264");
        // sc2
        WAITL(3); WAITV(10);
        DOT16(hA, wiA, wfA, g2, o2)
        LDGB(g2, "0"); LDGB(o2, "1024");           // sc6
        DSH(hA, "64"); DSW2(wiA, wfA, "4096", "12288");
        // sc3
        WAITL(3); WAITV(10);
        DOT16(hB, wiB, wfB, g3, o3)
        LDGB(g3, "2048"); LDGB(o3, "3072");        // sc7
        DSH(hB, "80"); DSW2(wiB, wfB, "5120", "13312");
        // sc4 (queue: x0-3 + 8 LDGB = 12; need g0,o0 -> wait 6)
        WAITL(3); WAITV(6);
        DOT16(hA, wiA, wfA, g0, o0)
        DSH(hA, "96"); DSW2(wiA, wfA, "6144", "14336");
        // sc5
        WAITL(3); WAITV(4);
        DOT16(hB, wiB, wfB, g1, o1)
        DSH(hB, "112"); DSW2(wiB, wfB, "7168", "15360");
        // sc6
        WAITL(3); WAITV(2);
        DOT16(hA, wiA, wfA, g2, o2)
        // sc7
        WAITL(0); WAITV(0);
        DOT16(hB, wiB, wfB, g3, o3)

        *(float4*)&part2[kh][r][0] =
            make_float4((float)ai, (float)af, (float)ag, (float)ao);
        __syncthreads();
        if (t < 256) {
            float4 q0 = *(const float4*)&part2[0][t][0];
            float4 q1 = *(const float4*)&part2[1][t][0];
            const float INV = 1.f / (2016.f * 127.f);
            float gi = fmaf(q0.x + q1.x, INV, x0);
            float gf = fmaf(q0.y + q1.y, INV, x1);
            float gg = fmaf(q0.z + q1.z, INV, x2);
            float go = fmaf(q0.w + q1.w, INV, x3);
            c = sigmf(gf) * c + sigmf(gi) * tanhfast(gg);
            float h = sigmf(go) * tanhfast(c);
            hs[t] = (unsigned char)(signed char)(int)rintf(h * 127.f);
            lob[(size_t)l * 512] = h;
        }
        __syncthreads();
        l += dl;
    }
#undef LDGA
#undef LDGB
#undef DSH
#undef DSW2
#undef WAITL
#undef WAITV
#undef DOT16
}

// ---------------- K3: emissions GEMM (unchanged) ----------------
__global__ __launch_bounds__(256) void emis_gemm(
    const float* __restrict__ lo, const float* __restrict__ w_out,
    const float* __restrict__ b_out, float* __restrict__ em)
{
    __shared__ float as[64][64];
    __shared__ float bs[64][64];
    const int tid = threadIdx.x;
    const int m0 = blockIdx.x * 64;
    const int mr = tid & 63;
    const int kq = tid >> 6;
    const int rb = (tid & 15) * 4;
    const int cb = (tid >> 4) * 4;
    float acc[4][4] = {};
    for (int kc = 0; kc < 8; ++kc) {
        const int k0 = kc * 64;
        #pragma unroll
        for (int i = 0; i < 4; ++i) {
            const int k = kq * 16 + 4 * i;
            float4 va = *(const float4*)&lo[(size_t)(m0 + mr) * 512 + k0 + k];
            as[k][mr] = va.x; as[k + 1][mr] = va.y; as[k + 2][mr] = va.z; as[k + 3][mr] = va.w;
            float4 vb = *(const float4*)&w_out[(size_t)mr * 512 + k0 + k];
            bs[k][mr] = vb.x; bs[k + 1][mr] = vb.y; bs[k + 2][mr] = vb.z; bs[k + 3][mr] = vb.w;
        }
        __syncthreads();
        #pragma unroll 8
        for (int kk = 0; kk < 64; ++kk) {
            float a[4], bb[4];
            *(float4*)a  = *(const float4*)&as[kk][rb];
            *(float4*)bb = *(const float4*)&bs[kk][cb];
            #pragma unroll
            for (int i = 0; i < 4; ++i)
                #pragma unroll
                for (int jj = 0; jj < 4; ++jj)
                    acc[i][jj] += a[i] * bb[jj];
        }
        __syncthreads();
    }
    float4 bo = *(const float4*)&b_out[cb];
    #pragma unroll
    for (int i = 0; i < 4; ++i) {
        float4 o = make_float4(acc[i][0] + bo.x, acc[i][1] + bo.y,
                               acc[i][2] + bo.z, acc[i][3] + bo.w);
        *(float4*)&em[(size_t)(m0 + rb + i) * 64 + cb] = o;
    }
}

// ---------------- K4: CRF numerator + forward algorithm (unchanged) ---------
__global__ __launch_bounds__(256) void crf_kernel(
    const float* __restrict__ em, const int* __restrict__ tags,
    const float* __restrict__ start_t, const float* __restrict__ end_t,
    const float* __restrict__ trans, float* __restrict__ nll)
{
    const int b = blockIdx.x;
    const int tid = threadIdx.x;
    const int j = tid & 63;
    const int q = tid >> 6;
    __shared__ float s_lds[64];
    __shared__ float part[4][64];
    __shared__ float m_sh, num_sh;
    float tr[16];
    #pragma unroll
    for (int ii = 0; ii < 16; ++ii) tr[ii] = trans[(q * 16 + ii) * 64 + j];
    const float* emb_b = em + (size_t)b * 8192;
    const int* tg_b = tags + b * 128;
    float numpart = 0.f;
    if (tid < 128) {
        int l = tid;
        int tg = tg_b[l];
        numpart = emb_b[l * 64 + tg];
        if (l < 127) numpart += trans[tg * 64 + tg_b[l + 1]];
        if (l == 0)  numpart += start_t[tg];
        if (l == 127) numpart += end_t[tg];
    }
    float red = numpart;
    #pragma unroll
    for (int off = 32; off >= 1; off >>= 1) red += __shfl_xor(red, off);
    if (j == 0) part[q][0] = red;
    if (q == 0) s_lds[j] = start_t[j] + emb_b[j];
    __syncthreads();
    if (tid == 0) num_sh = part[0][0] + part[1][0] + part[2][0] + part[3][0];
    __syncthreads();
    for (int l = 1; l < 128; ++l) {
        if (q == 0) {
            float v = s_lds[j];
            #pragma unroll
            for (int off = 32; off >= 1; off >>= 1) v = fmaxf(v, __shfl_xor(v, off));
            if (j == 0) m_sh = v;
        }
        __syncthreads();
        const float m = m_sh;
        float sv[16];
        #pragma unroll
        for (int t4 = 0; t4 < 4; ++t4) {
            float4 v = *(const float4*)&s_lds[q * 16 + 4 * t4];
            sv[4 * t4] = v.x; sv[4 * t4 + 1] = v.y; sv[4 * t4 + 2] = v.z; sv[4 * t4 + 3] = v.w;
        }
        float acc = 0.f;
        #pragma unroll
        for (int ii = 0; ii < 16; ++ii) acc += __expf(sv[ii] + tr[ii] - m);
        part[q][j] = acc;
        __syncthreads();
        if (q == 0) {
            float t = part[0][j] + part[1][j] + part[2][j] + part[3][j];
            s_lds[j] = m + __logf(t) + emb_b[l * 64 + j];
        }
    }
    if (q == 0) {
        float v = s_lds[j] + end_t[j];
        float mm = v;
        #pragma unroll
        for (int off = 32; off >= 1; off >>= 1) mm = fmaxf(mm, __shfl_xor(mm, off));
        float e = __expf(v - mm);
        #pragma unroll
        for (int off = 32; off >= 1; off >>= 1) e += __shfl_xor(e, off);
        if (j == 0) nll[b] = (mm + __logf(e)) - num_sh;
    }
}

// ---------------- K5: final mean ----------------
__global__ void finalize(const float* __restrict__ nll, float* __restrict__ out)
{
    int j = threadIdx.x;
    float v = nll[j];
    #pragma unroll
    for (int off = 32; off >= 1; off >>= 1) v += __shfl_xor(v, off);
    if (j == 0) out[0] = v * (1.f / 64.f);
}

extern "C" void kernel_launch(void* const* d_in, const int* in_sizes, int n_in,
                              void* d_out, int out_size, void* d_ws, size_t ws_size,
                              hipStream_t stream) {
    const int* sent      = (const int*)d_in[0];
    const int* tags      = (const int*)d_in[1];
    const float* emb     = (const float*)d_in[2];
    const float* w_ih_f  = (const float*)d_in[3];
    const float* w_hh_f  = (const float*)d_in[4];
    const float* b_ih_f  = (const float*)d_in[5];
    const float* b_hh_f  = (const float*)d_in[6];
    const float* w_ih_b  = (const float*)d_in[7];
    const float* w_hh_b  = (const float*)d_in[8];
    const float* b_ih_b  = (const float*)d_in[9];
    const float* b_hh_b  = (const float*)d_in[10];
    const float* w_out   = (const float*)d_in[11];
    const float* b_out   = (const float*)d_in[12];
    const float* start_t = (const float*)d_in[13];
    const float* end_t   = (const float*)d_in[14];
    const float* trans   = (const float*)d_in[15];

    float* ws = (float*)d_ws;
    float* xp        = ws + XP_OFF;
    float* lstm_out  = ws + LSTM_OFF;
    float* em        = ws + EM_OFF;
    unsigned int* w8 = (unsigned int*)(ws + WBF_OFF);
    float* nll       = ws + NLL_OFF;
    unsigned* bimg   = (unsigned*)(ws + BIMG_OFF);
    float* bias2     = ws + BIAS_OFF;

    cvt_whh_i8<<<dim3(512), dim3(256), 0, stream>>>(w_hh_f, w_hh_b, w8);
    prep_b<<<dim3(2048), dim3(64), 0, stream>>>(w_ih_f, w_ih_b,
        b_ih_f, b_hh_f, b_ih_b, b_hh_b, bimg, bias2);
    xp_gemm<<<dim3(64, 16), dim3(256), 0, stream>>>(sent, emb, bimg, bias2, xp);
    lstm_rec<<<dim3(128), dim3(512), 0, stream>>>(xp, w8, lstm_out);
    emis_gemm<<<dim3(128), dim3(256), 0, stream>>>(lstm_out, w_out, b_out, em);
    crf_kernel<<<dim3(64), dim3(256), 0, stream>>>(em, tags, start_t, end_t, trans, nll);
    finalize<<<dim3(1), dim3(64), 0, stream>>>(nll, (float*)d_out);
}

// Round 17
// 406.977 us; speedup vs baseline: 2.1814x; 1.0534x over previous
//
#include <hip/hip_runtime.h>

// Problem: BiLSTM-CRF tagger NLL (forward only).
// B=64, L=128, E=300, H=256 (per dir), 4H=1024, T=64, V=50000.
//
// ws layout (float units):
//   XP_OFF   = 0           : xp[2][8192][1024] f32
//   LSTM_OFF = 16777216    : lstm_out[8192][512]
//   EM_OFF   = 20971520    : emissions[8192][64] (B-frag image + bias2 during
//                            xp_gemm — dead until emis_gemm)
//   WBF_OFF  = 21495808    : w_hh int8, wave-coalesced uint4 layout (512 KB)
//   NLL_OFF  = 21757952    : per-batch nll [64]
//
// R16 landed: int8 dot4 recurrence, 214us, VGPR 88, DS-pipe bound
// (~2550cy/step of 4000). R17: g,o weights for sc4-7 pinned in 8 register
// quads (step-invariant; loaded once) -> no in-loop LDGB, L2 stream halved
// to 64KB/step, fewer bubbles. VGPR ~120 of the 512-thread 128 budget.

#define XP_OFF   0
#define LSTM_OFF 16777216
#define EM_OFF   20971520
#define WBF_OFF  21495808
#define NLL_OFF  21757952
#define BIMG_OFF EM_OFF
#define BIAS_OFF (EM_OFF + 500000)

typedef unsigned v4u __attribute__((ext_vector_type(4)));
typedef short bf16x8 __attribute__((ext_vector_type(8)));
typedef float f32x4 __attribute__((ext_vector_type(4)));

__device__ __forceinline__ float sigmf(float x) { return 1.f / (1.f + __expf(-x)); }
__device__ __forceinline__ float tanhfast(float x) {
    float t = __expf(2.f * x);
    return 1.f - 2.f / (t + 1.f);
}
__device__ __forceinline__ unsigned short f2bf(float f) {
    unsigned u = __float_as_uint(f);
    return (unsigned short)((u + 0x7fffu + ((u >> 16) & 1u)) >> 16);
}
__device__ __forceinline__ unsigned packbf(float a, float b) {
    return (unsigned)f2bf(a) | ((unsigned)f2bf(b) << 16);
}
__device__ __forceinline__ int dot4(int a, int b, int c) {
#if __has_builtin(__builtin_amdgcn_sdot4)
    return __builtin_amdgcn_sdot4(a, b, c, false);
#else
    int r = c;
    #pragma unroll
    for (int i = 0; i < 4; ++i) {
        int ai = (a << (24 - 8 * i)) >> 24;
        int bi = (b << (24 - 8 * i)) >> 24;
        r += ai * bi;
    }
    return r;
#endif
}
// int8 encode for w_hh (|w| <= 1/16 -> |w*2016| <= 126)
__device__ __forceinline__ unsigned ei8(float x) {
    float v = fminf(fmaxf(x * 2016.f, -127.f), 127.f);
    return (unsigned)(unsigned char)(signed char)(int)rintf(v);
}

// ---------------- K0: repack w_hh (f32 -> int8, scaled x2016) ---------------
// Quad index = half*16384 + ((dir*8 + w)*16 + q)*64 + ln  (R14/R16 layout).
//   half0 (i,f; LDS-cached): gate = q>>3, sc = q&7
//   half1 (g,o)            : gate = 2+(q&1), sc = q>>1
//     q0..7 = sc0-3 (streamed), q8..15 = sc4-7 (register-pinned)
//   dword i covers k = kh*128 + sc*16 + i*4 .. +3 of row gate*256+r,
//   thread t = w*64+ln: r = t&255, kh = t>>8.
__global__ __launch_bounds__(256) void cvt_whh_i8(
    const float* __restrict__ wf, const float* __restrict__ wb,
    unsigned int* __restrict__ out)
{
    int idx = blockIdx.x * 256 + threadIdx.x;   // dword 0..131071
    int i    = idx & 3;
    int ln   = (idx >> 2) & 63;
    int q    = (idx >> 8) & 15;
    int w    = (idx >> 12) & 7;
    int dir  = (idx >> 15) & 1;
    int half = (idx >> 16) & 1;
    const float* wsrc = dir ? wb : wf;
    int t = w * 64 + ln;
    int r = t & 255, kh = t >> 8;
    int g_, sc;
    if (half == 0) { g_ = q >> 3;       sc = q & 7;  }
    else           { g_ = 2 + (q & 1);  sc = q >> 1; }
    int row = g_ * 256 + r;
    int k0 = kh * 128 + sc * 16 + i * 4;
    const float* src = wsrc + (size_t)row * 256 + k0;
    unsigned o = 0;
    #pragma unroll
    for (int j = 0; j < 4; ++j) o |= ei8(src[j]) << (8 * j);
    out[idx] = o;
}

// ---------------- K0b: prep B fragment image + bias2 (unchanged) ------------
__global__ __launch_bounds__(64) void prep_b(
    const float* __restrict__ wf, const float* __restrict__ wb,
    const float* __restrict__ bif, const float* __restrict__ bhf,
    const float* __restrict__ bib, const float* __restrict__ bhb,
    unsigned* __restrict__ bimg, float* __restrict__ bias2)
{
    int n = blockIdx.x;
    int dir = n >> 10, nr = n & 1023;
    int k8 = threadIdx.x;
    if (k8 < 40) {
        const float* wsrc = dir ? wb : wf;
        float v[8];
        #pragma unroll
        for (int j = 0; j < 8; ++j) {
            int k = k8 * 8 + j;
            v[j] = (k < 300) ? wsrc[(size_t)nr * 300 + k] : 0.f;
        }
        int ntg = n >> 4, kt = k8 >> 2;
        int lane = ((k8 & 3) << 4) | (n & 15);
        unsigned* dst = bimg + (((size_t)(ntg * 10 + kt)) * 64 + lane) * 4;
        dst[0] = packbf(v[0], v[1]); dst[1] = packbf(v[2], v[3]);
        dst[2] = packbf(v[4], v[5]); dst[3] = packbf(v[6], v[7]);
    } else if (k8 == 40) {
        bias2[n] = (dir ? bib : bif)[nr] + (dir ? bhb : bhf)[nr];
    }
}

// ---------------- K1: xp GEMM via bf16 MFMA (unchanged, validated) ----------
__global__ __launch_bounds__(256) void xp_gemm(
    const int* __restrict__ sent, const float* __restrict__ emb,
    const unsigned* __restrict__ bimg, const float* __restrict__ bias2,
    float* __restrict__ xp)
{
    __shared__ __align__(16) unsigned short Alds[128 * 328];
    __shared__ int sidx[128];
    const int tid = threadIdx.x;
    const int m0 = blockIdx.x * 128;
    const int by = blockIdx.y;
    if (tid < 128) sidx[tid] = sent[m0 + tid];
    __syncthreads();
    #pragma unroll
    for (int i2 = 0; i2 < 5; ++i2) {
        int f2 = i2 * 256 + tid;
        int row = (f2 * 6554) >> 16;
        int d = f2 - row * 10;
        *(unsigned*)((char*)Alds + row * 656 + 600 + d * 4) = 0;
    }
    for (int it = 0; it < 38; ++it) {
        int f = it * 256 + tid;
        if (f < 9600) {
            int row = (int)(((unsigned)f * 55925u) >> 22);
            int c4 = f - row * 75;
            float4 v = *(const float4*)&emb[(size_t)sidx[row] * 300 + c4 * 4];
            uint2 p; p.x = packbf(v.x, v.y); p.y = packbf(v.z, v.w);
            *(uint2*)((char*)Alds + row * 656 + c4 * 8) = p;
        }
    }
    __syncthreads();
    const int l = tid & 63, wid = tid >> 6;
    const int wy = wid >> 1, wx = wid & 1;
    const int lhi = l >> 4, llo = l & 15;
    f32x4 acc[4][4];
    #pragma unroll
    for (int nt = 0; nt < 4; ++nt) {
        float bv = bias2[by * 128 + wx * 64 + nt * 16 + llo];
        #pragma unroll
        for (int mt = 0; mt < 4; ++mt) acc[mt][nt] = (f32x4){bv, bv, bv, bv};
    }
    const char* abase = (const char*)Alds + (size_t)(wy * 64 + llo) * 656 + lhi * 16;
    const unsigned* bb = bimg + (((size_t)((by * 8 + wx * 4) * 10)) * 64 + l) * 4;
    for (int kt = 0; kt < 10; ++kt) {
        bf16x8 a[4], b[4];
        #pragma unroll
        for (int mt = 0; mt < 4; ++mt)
            a[mt] = *(const bf16x8*)(abase + mt * 16 * 656 + kt * 64);
        #pragma unroll
        for (int nt = 0; nt < 4; ++nt)
            b[nt] = *(const bf16x8*)(bb + (nt * 10 + kt) * 256);
        #pragma unroll
        for (int mt = 0; mt < 4; ++mt)
            #pragma unroll
            for (int nt = 0; nt < 4; ++nt)
                acc[mt][nt] = __builtin_amdgcn_mfma_f32_16x16x32_bf16(
                    a[mt], b[nt], acc[mt][nt], 0, 0, 0);
    }
    const int dir = by >> 3;
    const int n0 = (by & 7) * 128 + wx * 64;
    float* outp = xp + (size_t)dir * 8388608;
    #pragma unroll
    for (int mt = 0; mt < 4; ++mt) {
        int row = m0 + wy * 64 + mt * 16 + lhi * 4;
        #pragma unroll
        for (int nt = 0; nt < 4; ++nt) {
            int col = n0 + nt * 16 + llo;
            #pragma unroll
            for (int j = 0; j < 4; ++j)
                outp[(size_t)(row + j) * 1024 + col] = acc[mt][nt][j];
        }
    }
}

// ---------------- K2: LSTM recurrence, int8 dot4 + pinned g,o sc4-7 ---------
// 128 blocks = (dir, batch), dir = (bid&7)>>2.  512 threads.
// Thread t: r = t&255 (unit), kh = t>>8. Owns all 4 gates of unit r over
// k in [kh*128, kh*128+128) = 8 subchunks of 16 k.
// i,f weights LDS-cached (128 KB); g,o sc0-3 streamed from L2 under exact
// counted vmcnt; g,o sc4-7 pinned in 8 register quads (loaded once);
// h int8 in LDS (1 uniform b128 per sc).
__global__ __launch_bounds__(512) void lstm_rec(
    const float* __restrict__ xp, const unsigned int* __restrict__ w8,
    float* __restrict__ lstm_out)
{
    const int bid = blockIdx.x;
    const int r8  = bid & 7;
    const int dir = r8 >> 2;
    const int b   = ((bid >> 3) << 2) | (r8 & 3);
    const int t  = threadIdx.x;
    const int w  = t >> 6;      // 0..7
    const int ln = t & 63;
    const int r  = t & 255;
    const int kh = t >> 8;      // 0..1, uniform per wave
    __shared__ __align__(16) unsigned char hs[256];    // h int8 (x127)
    __shared__ __align__(16) float part2[2][256][4];   // [kh][unit][gate]
    __shared__ v4u wl[8192];                           // 128 KB cached i,f

    const v4u* w4 = (const v4u*)w8;
    #pragma unroll
    for (int q = 0; q < 16; ++q)
        wl[(w * 16 + q) * 64 + ln] = w4[((size_t)(dir * 8 + w) * 16 + q) * 64 + ln];

    // streamed base (q0..7 = sc0-3 g,o), centered at q4 (13-bit signed offsets)
    const v4u* sbA = w4 + 16384 + ((size_t)(dir * 8 + w) * 16 + 4)  * 64 + ln;
    // pinned base (q8..15 = sc4-7 g,o), centered at q12
    const v4u* sbB = w4 + 16384 + ((size_t)(dir * 8 + w) * 16 + 12) * 64 + ln;
    const unsigned wofs = (unsigned)(size_t)&wl[0] + (unsigned)(w * 16384 + ln * 16);
    const unsigned hofs = (unsigned)(size_t)&hs[0] + (unsigned)(kh * 128);

    // pin sc4-7 g,o quads in registers once (step-invariant)
    v4u p4g, p4o, p5g, p5o, p6g, p6o, p7g, p7o;
    asm volatile(
        "global_load_dwordx4 %0, %8, off offset:-4096\n\t"
        "global_load_dwordx4 %1, %8, off offset:-3072\n\t"
        "global_load_dwordx4 %2, %8, off offset:-2048\n\t"
        "global_load_dwordx4 %3, %8, off offset:-1024\n\t"
        "global_load_dwordx4 %4, %8, off\n\t"
        "global_load_dwordx4 %5, %8, off offset:1024\n\t"
        "global_load_dwordx4 %6, %8, off offset:2048\n\t"
        "global_load_dwordx4 %7, %8, off offset:3072\n\t"
        "s_waitcnt vmcnt(0)"
        : "=&v"(p4g), "=&v"(p4o), "=&v"(p5g), "=&v"(p5o),
          "=&v"(p6g), "=&v"(p6o), "=&v"(p7g), "=&v"(p7o)
        : "v"(sbB));

    float c = 0.f;
    if (t < 64) ((unsigned*)hs)[t] = 0;
    const float* xpb = xp + (size_t)dir * 8388608 + (size_t)b * 131072;
    const int dl = dir ? -1 : 1;
    int l = dir ? 127 : 0;
    float* lob = lstm_out + (size_t)b * 65536 + dir * 256 + r;
    __syncthreads();

#define LDGA(reg, off) asm volatile("global_load_dwordx4 %0, %1, off offset:" off \
                                    : "=&v"(reg) : "v"(sbA))
#define DSH(reg, off) asm volatile("ds_read_b128 %0, %1 offset:" off \
                                   : "=&v"(reg) : "v"(hofs))
#define DSW2(ri, rf, oi, of) asm volatile( \
    "ds_read_b128 %0, %2 offset:" oi "\n\t" \
    "ds_read_b128 %1, %2 offset:" of \
    : "=&v"(ri), "=&v"(rf) : "v"(wofs))
#define WAITL(N) { asm volatile("s_waitcnt lgkmcnt(" #N ")" ::: "memory"); \
                   __builtin_amdgcn_sched_barrier(0); }
#define WAITV(N) { asm volatile("s_waitcnt vmcnt(" #N ")" ::: "memory"); \
                   __builtin_amdgcn_sched_barrier(0); }
#define DOT16(H, WI, WF, G, O) { \
    ai = dot4((int)H[0], (int)WI[0], ai); af = dot4((int)H[0], (int)WF[0], af); \
    ag = dot4((int)H[0], (int)G[0], ag);  ao = dot4((int)H[0], (int)O[0], ao); \
    ai = dot4((int)H[1], (int)WI[1], ai); af = dot4((int)H[1], (int)WF[1], af); \
    ag = dot4((int)H[1], (int)G[1], ag);  ao = dot4((int)H[1], (int)O[1], ao); \
    ai = dot4((int)H[2], (int)WI[2], ai); af = dot4((int)H[2], (int)WF[2], af); \
    ag = dot4((int)H[2], (int)G[2], ag);  ao = dot4((int)H[2], (int)O[2], ao); \
    ai = dot4((int)H[3], (int)WI[3], ai); af = dot4((int)H[3], (int)WF[3], af); \
    ag = dot4((int)H[3], (int)G[3], ag);  ao = dot4((int)H[3], (int)O[3], ao); }

    for (int s = 0; s < 128; ++s) {
        // ---- issue 8 streamed g/o quads (sc0-3, vmcnt-oldest), then xp ----
        v4u g0, o0, g1, o1, g2, o2, g3, o3;
        LDGA(g0, "-4096"); LDGA(o0, "-3072"); LDGA(g1, "-2048"); LDGA(o1, "-1024");
        LDGA(g2, "0");     LDGA(o2, "1024");  LDGA(g3, "2048");  LDGA(o3, "3072");
        float x0, x1, x2, x3;                 // all threads (uniform vmcnt queue)
        {
            const float* xcur = xpb + (size_t)l * 1024 + r;
            asm volatile("global_load_dword %0, %4, off\n\t"
                         "global_load_dword %1, %4, off offset:1024\n\t"
                         "global_load_dword %2, %4, off offset:2048\n\t"
                         "global_load_dword %3, %4, off offset:3072"
                         : "=&v"(x0), "=&v"(x1), "=&v"(x2), "=&v"(x3) : "v"(xcur));
        }
        // VMEM queue: g0,o0,g1,o1,g2,o2,g3,o3,x0..x3 (12)
        int ai = 0, af = 0, ag = 0, ao = 0;
        v4u hA, hB, wiA, wfA, wiB, wfB;
        DSH(hA, "0");  DSW2(wiA, wfA, "0", "8192");
        DSH(hB, "16"); DSW2(wiB, wfB, "1024", "9216");
        // sc0
        WAITL(3); WAITV(10);
        DOT16(hA, wiA, wfA, g0, o0)
        DSH(hA, "32"); DSW2(wiA, wfA, "2048", "10240");
        // sc1
        WAITL(3); WAITV(8);
        DOT16(hB, wiB, wfB, g1, o1)
        DSH(hB, "48"); DSW2(wiB, wfB, "3072", "11264");
        // sc2
        WAITL(3); WAITV(6);
        DOT16(hA, wiA, wfA, g2, o2)
        DSH(hA, "64"); DSW2(wiA, wfA, "4096", "12288");
        // sc3
        WAITL(3); WAITV(4);
        DOT16(hB, wiB, wfB, g3, o3)
        DSH(hB, "80"); DSW2(wiB, wfB, "5120", "13312");
        // sc4 (pinned weights, no VMEM wait)
        WAITL(3);
        DOT16(hA, wiA, wfA, p4g, p4o)
        DSH(hA, "96"); DSW2(wiA, wfA, "6144", "14336");
        // sc5
        WAITL(3);
        DOT16(hB, wiB, wfB, p5g, p5o)
        DSH(hB, "112"); DSW2(wiB, wfB, "7168", "15360");
        // sc6
        WAITL(3);
        DOT16(hA, wiA, wfA, p6g, p6o)
        // sc7
        WAITL(0);
        DOT16(hB, wiB, wfB, p7g, p7o)
        WAITV(0);          // drain xp (uniform per-wave queue)

        *(float4*)&part2[kh][r][0] =
            make_float4((float)ai, (float)af, (float)ag, (float)ao);
        __syncthreads();
        if (t < 256) {
            float4 q0 = *(const float4*)&part2[0][t][0];
            float4 q1 = *(const float4*)&part2[1][t][0];
            const float INV = 1.f / (2016.f * 127.f);
            float gi = fmaf(q0.x + q1.x, INV, x0);
            float gf = fmaf(q0.y + q1.y, INV, x1);
            float gg = fmaf(q0.z + q1.z, INV, x2);
            float go = fmaf(q0.w + q1.w, INV, x3);
            c = sigmf(gf) * c + sigmf(gi) * tanhfast(gg);
            float h = sigmf(go) * tanhfast(c);
            hs[t] = (unsigned char)(signed char)(int)rintf(h * 127.f);
            lob[(size_t)l * 512] = h;
        }
        __syncthreads();
        l += dl;
    }
#undef LDGA
#undef DSH
#undef DSW2
#undef WAITL
#undef WAITV
#undef DOT16
}

// ---------------- K3: emissions GEMM (unchanged) ----------------
__global__ __launch_bounds__(256) void emis_gemm(
    const float* __restrict__ lo, const float* __restrict__ w_out,
    const float* __restrict__ b_out, float* __restrict__ em)
{
    __shared__ float as[64][64];
    __shared__ float bs[64][64];
    const int tid = threadIdx.x;
    const int m0 = blockIdx.x * 64;
    const int mr = tid & 63;
    const int kq = tid >> 6;
    const int rb = (tid & 15) * 4;
    const int cb = (tid >> 4) * 4;
    float acc[4][4] = {};
    for (int kc = 0; kc < 8; ++kc) {
        const int k0 = kc * 64;
        #pragma unroll
        for (int i = 0; i < 4; ++i) {
            const int k = kq * 16 + 4 * i;
            float4 va = *(const float4*)&lo[(size_t)(m0 + mr) * 512 + k0 + k];
            as[k][mr] = va.x; as[k + 1][mr] = va.y; as[k + 2][mr] = va.z; as[k + 3][mr] = va.w;
            float4 vb = *(const float4*)&w_out[(size_t)mr * 512 + k0 + k];
            bs[k][mr] = vb.x; bs[k + 1][mr] = vb.y; bs[k + 2][mr] = vb.z; bs[k + 3][mr] = vb.w;
        }
        __syncthreads();
        #pragma unroll 8
        for (int kk = 0; kk < 64; ++kk) {
            float a[4], bb[4];
            *(float4*)a  = *(const float4*)&as[kk][rb];
            *(float4*)bb = *(const float4*)&bs[kk][cb];
            #pragma unroll
            for (int i = 0; i < 4; ++i)
                #pragma unroll
                for (int jj = 0; jj < 4; ++jj)
                    acc[i][jj] += a[i] * bb[jj];
        }
        __syncthreads();
    }
    float4 bo = *(const float4*)&b_out[cb];
    #pragma unroll
    for (int i = 0; i < 4; ++i) {
        float4 o = make_float4(acc[i][0] + bo.x, acc[i][1] + bo.y,
                               acc[i][2] + bo.z, acc[i][3] + bo.w);
        *(float4*)&em[(size_t)(m0 + rb + i) * 64 + cb] = o;
    }
}

// ---------------- K4: CRF numerator + forward algorithm (unchanged) ---------
__global__ __launch_bounds__(256) void crf_kernel(
    const float* __restrict__ em, const int* __restrict__ tags,
    const float* __restrict__ start_t, const float* __restrict__ end_t,
    const float* __restrict__ trans, float* __restrict__ nll)
{
    const int b = blockIdx.x;
    const int tid = threadIdx.x;
    const int j = tid & 63;
    const int q = tid >> 6;
    __shared__ float s_lds[64];
    __shared__ float part[4][64];
    __shared__ float m_sh, num_sh;
    float tr[16];
    #pragma unroll
    for (int ii = 0; ii < 16; ++ii) tr[ii] = trans[(q * 16 + ii) * 64 + j];
    const float* emb_b = em + (size_t)b * 8192;
    const int* tg_b = tags + b * 128;
    float numpart = 0.f;
    if (tid < 128) {
        int l = tid;
        int tg = tg_b[l];
        numpart = emb_b[l * 64 + tg];
        if (l < 127) numpart += trans[tg * 64 + tg_b[l + 1]];
        if (l == 0)  numpart += start_t[tg];
        if (l == 127) numpart += end_t[tg];
    }
    float red = numpart;
    #pragma unroll
    for (int off = 32; off >= 1; off >>= 1) red += __shfl_xor(red, off);
    if (j == 0) part[q][0] = red;
    if (q == 0) s_lds[j] = start_t[j] + emb_b[j];
    __syncthreads();
    if (tid == 0) num_sh = part[0][0] + part[1][0] + part[2][0] + part[3][0];
    __syncthreads();
    for (int l = 1; l < 128; ++l) {
        if (q == 0) {
            float v = s_lds[j];
            #pragma unroll
            for (int off = 32; off >= 1; off >>= 1) v = fmaxf(v, __shfl_xor(v, off));
            if (j == 0) m_sh = v;
        }
        __syncthreads();
        const float m = m_sh;
        float sv[16];
        #pragma unroll
        for (int t4 = 0; t4 < 4; ++t4) {
            float4 v = *(const float4*)&s_lds[q * 16 + 4 * t4];
            sv[4 * t4] = v.x; sv[4 * t4 + 1] = v.y; sv[4 * t4 + 2] = v.z; sv[4 * t4 + 3] = v.w;
        }
        float acc = 0.f;
        #pragma unroll
        for (int ii = 0; ii < 16; ++ii) acc += __expf(sv[ii] + tr[ii] - m);
        part[q][j] = acc;
        __syncthreads();
        if (q == 0) {
            float t = part[0][j] + part[1][j] + part[2][j] + part[3][j];
            s_lds[j] = m + __logf(t) + emb_b[l * 64 + j];
        }
    }
    if (q == 0) {
        float v = s_lds[j] + end_t[j];
        float mm = v;
        #pragma unroll
        for (int off = 32; off >= 1; off >>= 1) mm = fmaxf(mm, __shfl_xor(mm, off));
        float e = __expf(v - mm);
        #pragma unroll
        for (int off = 32; off >= 1; off >>= 1) e += __shfl_xor(e, off);
        if (j == 0) nll[b] = (mm + __logf(e)) - num_sh;
    }
}

// ---------------- K5: final mean ----------------
__global__ void finalize(const float* __restrict__ nll, float* __restrict__ out)
{
    int j = threadIdx.x;
    float v = nll[j];
    #pragma unroll
    for (int off = 32; off >= 1; off >>= 1) v += __shfl_xor(v, off);
    if (j == 0) out[0] = v * (1.f / 64.f);
}

extern "C" void kernel_launch(void* const* d_in, const int* in_sizes, int n_in,
                              void* d_out, int out_size, void* d_ws, size_t ws_size,
                              hipStream_t stream) {
    const int* sent      = (const int*)d_in[0];
    const int* tags      = (const int*)d_in[1];
    const float* emb     = (const float*)d_in[2];
    const float* w_ih_f  = (const float*)d_in[3];
    const float* w_hh_f  = (const float*)d_in[4];
    const float* b_ih_f  = (const float*)d_in[5];
    const float* b_hh_f  = (const float*)d_in[6];
    const float* w_ih_b  = (const float*)d_in[7];
    const float* w_hh_b  = (const float*)d_in[8];
    const float* b_ih_b  = (const float*)d_in[9];
    const float* b_hh_b  = (const float*)d_in[10];
    const float* w_out   = (const float*)d_in[11];
    const float* b_out   = (const float*)d_in[12];
    const float* start_t = (const float*)d_in[13];
    const float* end_t   = (const float*)d_in[14];
    const float* trans   = (const float*)d_in[15];

    float* ws = (float*)d_ws;
    float* xp        = ws + XP_OFF;
    float* lstm_out  = ws + LSTM_OFF;
    float* em        = ws + EM_OFF;
    unsigned int* w8 = (unsigned int*)(ws + WBF_OFF);
    float* nll       = ws + NLL_OFF;
    unsigned* bimg   = (unsigned*)(ws + BIMG_OFF);
    float* bias2     = ws + BIAS_OFF;

    cvt_whh_i8<<<dim3(512), dim3(256), 0, stream>>>(w_hh_f, w_hh_b, w8);
    prep_b<<<dim3(2048), dim3(64), 0, stream>>>(w_ih_f, w_ih_b,
        b_ih_f, b_hh_f, b_ih_b, b_hh_b, bimg, bias2);
    xp_gemm<<<dim3(64, 16), dim3(256), 0, stream>>>(sent, emb, bimg, bias2, xp);
    lstm_rec<<<dim3(128), dim3(512), 0, stream>>>(xp, w8, lstm_out);
    emis_gemm<<<dim3(128), dim3(256), 0, stream>>>(lstm_out, w_out, b_out, em);
    crf_kernel<<<dim3(64), dim3(256), 0, stream>>>(em, tags, start_t, end_t, trans, nll);
    finalize<<<dim3(1), dim3(64), 0, stream>>>(nll, (float*)d_out);
}